// Round 4
// baseline (274.683 us; speedup 1.0000x reference)
//
#include <hip/hip_runtime.h>

#define Bdim 256
#define Tdim 512
#define Kdim 128
#define NT   256   // thread (j4 = tid>>3, g = tid&7): 4 columns x 16-row slice

// Raw barrier: drain LDS ops only (NOT vmcnt) so global prefetches stay in
// flight across steps; then s_barrier. "memory" stops compiler reordering.
#define BAR() asm volatile("s_waitcnt lgkmcnt(0)\n\ts_barrier" ::: "memory")

// Quad-lane butterfly add via DPP. CTRL 0xB1 = quad_perm [1,0,3,2] (xor 1);
// 0x4E = [2,3,0,1] (xor 2). Control must be a constant -> template param.
template <int CTRL>
__device__ __forceinline__ float quad_add(float v) {
    int r = __builtin_amdgcn_update_dpp(0, __float_as_int(v), CTRL, 0xF, 0xF, true);
    return v + __int_as_float(r);
}

// One block per batch element, 256 threads (4 waves).
// Thread (j4, g) accumulates columns {4j4..4j4+3} over i in [16g, 16g+16):
// 64 FMAs on a 16x4 E-fragment (64 VGPRs) fed by 4 float4 LDS reads -> LDS
// return traffic is 16 KB/step (4x less than the 1-column-per-thread layout).
// Reduce over the 8 g-groups: 2 DPP quad-adds per acc, 3 cndmask select,
// 1 ds_swizzle xor-4. alpha in LINEAR space, renormalized by A[0] each step.
__global__ __launch_bounds__(NT, 1) void crf_nll_kernel(
    const float* __restrict__ logits,   // B*T*K fp32
    const int*   __restrict__ labels,   // B*T   int32
    const int*   __restrict__ seq_lens, // B     int32
    const float* __restrict__ trans,    // K*K   fp32
    float* __restrict__ out)            // 1     fp32 (pre-zeroed)
{
    const int b   = blockIdx.x;
    const int tid = threadIdx.x;
    const int j4  = tid >> 3;           // column set 0..31 (cols 4j4..4j4+3)
    const int g   = tid & 7;            // i-slice group 0..7
    const int cj  = 4 * j4 + (g & 3);   // this lane's write/logit column
    const int L   = seq_lens[b];        // 1..T (uniform per block)

    __shared__ float pbuf[2][Kdim];
    __shared__ float sred[NT / 64];
    __shared__ float ared[NT / 64];

    const int*   lab_b   = labels + (size_t)b * Tdim;
    const float* logit_b = logits + (size_t)b * Tdim * Kdim;

    // ---- E fragment (16 rows x 4 cols), read-rotated by (ii4+g)&3 so the 8
    // distinct float4 LDS addresses per read-instruction cover all 32 banks:
    // e[ii4][ci][c] = exp(trans[(16g + 4*((ii4+g)&3) + ci) * K + 4j4 + c])
    float e[4][4][4];
    #pragma unroll
    for (int ii4 = 0; ii4 < 4; ++ii4) {
        const int row0 = 16 * g + (((ii4 + g) & 3) << 2);
        #pragma unroll
        for (int ci = 0; ci < 4; ++ci) {
            const float4 tr =
                *(const float4*)&trans[(size_t)(row0 + ci) * Kdim + 4 * j4];
            e[ii4][ci][0] = __expf(tr.x);
            e[ii4][ci][1] = __expf(tr.y);
            e[ii4][ci][2] = __expf(tr.z);
            e[ii4][ci][3] = __expf(tr.w);
        }
    }

    // ---- gold-path score: 2 timesteps per thread ----
    float s = 0.f;
    #pragma unroll
    for (int t0 = 0; t0 < Tdim; t0 += NT) {
        const int t = t0 + tid;
        if (t < L) {
            const int lb = lab_b[t];
            s += logit_b[(size_t)t * Kdim + lb];
            if (t >= 1) s += trans[lab_b[t - 1] * Kdim + lb];
        }
    }
    #pragma unroll
    for (int o = 32; o > 0; o >>= 1) s += __shfl_down(s, o, 64);
    if ((tid & 63) == 0) sred[tid >> 6] = s;

    // ---- init alpha (t = 0), linear space; g<4 lanes own a column ----
    float a = 0.f, off = 0.f;
    if (g < 4) {
        a = __expf(logit_b[cj]);
        pbuf[0][cj] = a;
    }
    int cb = 0;
    __syncthreads();

    float score = 0.f;
    if (tid == 0) {
        #pragma unroll
        for (int w = 0; w < NT / 64; ++w) score += sred[w];
    }

    // ---- prefetch first logit chunk (t = 1..8), this lane's column ----
    float curl[8], nxtl[8];
    #pragma unroll
    for (int u = 0; u < 8; ++u) {
        const int tt = 1 + u;
        curl[u] = (tt < Tdim) ? logit_b[(size_t)tt * Kdim + cj] : 0.f;
    }

    // ---- forward recursion ----
    for (int tb = 1; tb < L; tb += 8) {
        #pragma unroll
        for (int u = 0; u < 8; ++u) {        // prefetch next chunk
            const int tt = tb + 8 + u;
            nxtl[u] = (tt < Tdim) ? logit_b[(size_t)tt * Kdim + cj] : 0.f;
        }
        #pragma unroll
        for (int u = 0; u < 8; ++u) {
            const int t = tb + u;
            if (t < L) {                     // uniform per block
                const float4* p4 = (const float4*)pbuf[cb];
                const float p0 = pbuf[cb][0];        // uniform broadcast read
                const float lp0 = __logf(p0);        // off critical path
                const float sc  = __expf(curl[u] - lp0);
                float acc0 = 0.f, acc1 = 0.f, acc2 = 0.f, acc3 = 0.f;
                #pragma unroll
                for (int ii4 = 0; ii4 < 4; ++ii4) {
                    const float4 p = p4[(g << 2) + ((ii4 + g) & 3)];
                    acc0 = fmaf(p.x, e[ii4][0][0], acc0);
                    acc1 = fmaf(p.x, e[ii4][0][1], acc1);
                    acc2 = fmaf(p.x, e[ii4][0][2], acc2);
                    acc3 = fmaf(p.x, e[ii4][0][3], acc3);
                    acc0 = fmaf(p.y, e[ii4][1][0], acc0);
                    acc1 = fmaf(p.y, e[ii4][1][1], acc1);
                    acc2 = fmaf(p.y, e[ii4][1][2], acc2);
                    acc3 = fmaf(p.y, e[ii4][1][3], acc3);
                    acc0 = fmaf(p.z, e[ii4][2][0], acc0);
                    acc1 = fmaf(p.z, e[ii4][2][1], acc1);
                    acc2 = fmaf(p.z, e[ii4][2][2], acc2);
                    acc3 = fmaf(p.z, e[ii4][2][3], acc3);
                    acc0 = fmaf(p.w, e[ii4][3][0], acc0);
                    acc1 = fmaf(p.w, e[ii4][3][1], acc1);
                    acc2 = fmaf(p.w, e[ii4][3][2], acc2);
                    acc3 = fmaf(p.w, e[ii4][3][3], acc3);
                }
                off += lp0;
                // intra-quad butterfly: all 4 quad lanes get all 4 col sums
                acc0 = quad_add<0xB1>(acc0); acc0 = quad_add<0x4E>(acc0);
                acc1 = quad_add<0xB1>(acc1); acc1 = quad_add<0x4E>(acc1);
                acc2 = quad_add<0xB1>(acc2); acc2 = quad_add<0x4E>(acc2);
                acc3 = quad_add<0xB1>(acc3); acc3 = quad_add<0x4E>(acc3);
                // select this lane's column (c = g&3), then xor-4 across quads
                float sel  = (g & 1) ? acc1 : acc0;
                float selh = (g & 1) ? acc3 : acc2;
                sel = (g & 2) ? selh : sel;
                sel += __int_as_float(__builtin_amdgcn_ds_swizzle(
                           __float_as_int(sel), 0x101F));   // xor 4, and 0x1F
                const float anew = sel * sc;
                if (g < 4) {
                    a = anew;
                    pbuf[cb ^ 1][cj] = anew;
                }
                cb ^= 1;
                BAR();                       // lgkm-only barrier per step
            }
        }
        #pragma unroll
        for (int u = 0; u < 8; ++u) curl[u] = nxtl[u];
    }

    // ---- log_z = off + log(sum_j A[j]); nll = log_z - score ----
    float as = (g < 4) ? a : 0.f;
    #pragma unroll
    for (int o = 32; o > 0; o >>= 1) as += __shfl_down(as, o, 64);
    if ((tid & 63) == 0) ared[tid >> 6] = as;
    __syncthreads();
    if (tid == 0) {
        float tot = 0.f;
        #pragma unroll
        for (int w = 0; w < NT / 64; ++w) tot += ared[w];
        const float logz = off + __logf(tot);
        atomicAdd(out, logz - score);
    }
}

extern "C" void kernel_launch(void* const* d_in, const int* in_sizes, int n_in,
                              void* d_out, int out_size, void* d_ws, size_t ws_size,
                              hipStream_t stream) {
    const float* logits   = (const float*)d_in[0];
    const int*   labels   = (const int*)d_in[1];
    const int*   seq_lens = (const int*)d_in[2];
    const float* trans    = (const float*)d_in[3];
    float* out = (float*)d_out;

    (void)hipMemsetAsync(out, 0, sizeof(float), stream);
    crf_nll_kernel<<<dim3(Bdim), dim3(NT), 0, stream>>>(
        logits, labels, seq_lens, trans, out);
}

// Round 5
// 273.250 us; speedup vs baseline: 1.0052x; 1.0052x over previous
//
#include <hip/hip_runtime.h>

#define Bdim 256
#define Tdim 512
#define Kdim 128
#define NT   512   // thread (j4 = tid>>4, g = tid&15): 4 columns x 8-row slice

// Raw barrier: drain LDS ops only (NOT vmcnt) so global prefetches stay in
// flight across steps; then s_barrier. "memory" stops compiler reordering.
#define BAR() asm volatile("s_waitcnt lgkmcnt(0)\n\ts_barrier" ::: "memory")

// DPP butterfly add. 0xB1 = quad_perm [1,0,3,2] (xor 1); 0x4E = [2,3,0,1]
// (xor 2); 0x124 = row_ror:4; 0x128 = row_ror:8 (rows are 16 lanes).
// quad(xor1)+quad(xor2)+ror4+ror8 sums all 16 lanes of each row.
template <int CTRL>
__device__ __forceinline__ float dpp_add(float v) {
    int r = __builtin_amdgcn_update_dpp(0, __float_as_int(v), CTRL, 0xF, 0xF, true);
    return v + __int_as_float(r);
}

// One block per batch element, 512 threads (8 waves).
// Thread (j4, g) accumulates columns {4j4..4j4+3} over rows [8g, 8g+8):
// 32 FMAs on a 8x4 E-fragment (32 VGPRs — the size round 3 proved stays
// register-resident) fed by 2 float4 LDS reads. DS insts/step/CU: 16 reads
// + 8 writes (vs 72 in round 3 — DS pipe was the ~770cy/step bottleneck).
// Reduce over the 16 g-groups entirely in DPP (no DS pipe).
// alpha in LINEAR space, renormalized by A[0] each step.
__global__ __launch_bounds__(NT, 1) void crf_nll_kernel(
    const float* __restrict__ logits,   // B*T*K fp32
    const int*   __restrict__ labels,   // B*T   int32
    const int*   __restrict__ seq_lens, // B     int32
    const float* __restrict__ trans,    // K*K   fp32
    float* __restrict__ out)            // 1     fp32 (pre-zeroed)
{
    const int b   = blockIdx.x;
    const int tid = threadIdx.x;
    const int j4  = tid >> 4;           // column set 0..31 (cols 4j4..4j4+3)
    const int g   = tid & 15;           // row-slice group 0..15
    const int cj  = 4 * j4 + (g & 3);   // this lane's write/logit column
    const int L   = seq_lens[b];        // 1..T (uniform per block)

    __shared__ float pbuf[2][Kdim];
    __shared__ float sred[NT / 64];
    __shared__ float ared[NT / 64];

    const int*   lab_b   = labels + (size_t)b * Tdim;
    const float* logit_b = logits + (size_t)b * Tdim * Kdim;

    // ---- E fragment (8 rows x 4 cols). Read-instruction ii accesses float4
    // index f = 2g + (((g>>2)&1)^ii): the 16 distinct addresses per inst
    // cover the 8 bank-quads exactly twice (2-way aliasing = free).
    float e[2][4][4];
    #pragma unroll
    for (int ii = 0; ii < 2; ++ii) {
        const int f = (g << 1) + (((g >> 2) & 1) ^ ii);
        #pragma unroll
        for (int ci = 0; ci < 4; ++ci) {
            const float4 tr =
                *(const float4*)&trans[(size_t)(4 * f + ci) * Kdim + 4 * j4];
            e[ii][ci][0] = __expf(tr.x);
            e[ii][ci][1] = __expf(tr.y);
            e[ii][ci][2] = __expf(tr.z);
            e[ii][ci][3] = __expf(tr.w);
        }
    }
    // Pin the fragment into VGPRs (guards against spill/remat — round 4's
    // silent failure mode: VGPR_Count 60 < fragment size).
    #pragma unroll
    for (int ii = 0; ii < 2; ++ii)
        #pragma unroll
        for (int ci = 0; ci < 4; ++ci)
            #pragma unroll
            for (int c = 0; c < 4; ++c)
                asm volatile("" : "+v"(e[ii][ci][c]));

    // ---- gold-path score: thread t = tid handles one timestep ----
    float s = 0.f;
    {
        const int t = tid;
        if (t < L) {
            const int lb = lab_b[t];
            s = logit_b[(size_t)t * Kdim + lb];
            if (t >= 1) s += trans[lab_b[t - 1] * Kdim + lb];
        }
    }
    #pragma unroll
    for (int o = 32; o > 0; o >>= 1) s += __shfl_down(s, o, 64);
    if ((tid & 63) == 0) sred[tid >> 6] = s;

    // ---- init alpha (t = 0), linear space; g<4 lanes own a column ----
    float a = 0.f, off = 0.f;
    if (g < 4) {
        a = __expf(logit_b[cj]);
        pbuf[0][cj] = a;
    }
    int cb = 0;
    __syncthreads();

    float score = 0.f;
    if (tid == 0) {
        #pragma unroll
        for (int w = 0; w < NT / 64; ++w) score += sred[w];
    }

    // ---- prefetch first logit chunk (t = 1..8), this lane's column ----
    float curl[8], nxtl[8];
    #pragma unroll
    for (int u = 0; u < 8; ++u) {
        const int tt = 1 + u;
        curl[u] = (tt < Tdim) ? logit_b[(size_t)tt * Kdim + cj] : 0.f;
    }

    // ---- forward recursion ----
    for (int tb = 1; tb < L; tb += 8) {
        #pragma unroll
        for (int u = 0; u < 8; ++u) {        // prefetch next chunk
            const int tt = tb + 8 + u;
            nxtl[u] = (tt < Tdim) ? logit_b[(size_t)tt * Kdim + cj] : 0.f;
        }
        #pragma unroll
        for (int u = 0; u < 8; ++u) {
            const int t = tb + u;
            if (t < L) {                     // uniform per block
                const float4* p4 = (const float4*)pbuf[cb];
                const float p0  = pbuf[cb][0];       // uniform broadcast read
                const float lp0 = __logf(p0);        // off critical path
                const float sc  = __expf(curl[u] - lp0);
                float acc0 = 0.f, acc1 = 0.f, acc2 = 0.f, acc3 = 0.f;
                #pragma unroll
                for (int ii = 0; ii < 2; ++ii) {
                    const float4 p = p4[(g << 1) + (((g >> 2) & 1) ^ ii)];
                    acc0 = fmaf(p.x, e[ii][0][0], acc0);
                    acc1 = fmaf(p.x, e[ii][0][1], acc1);
                    acc2 = fmaf(p.x, e[ii][0][2], acc2);
                    acc3 = fmaf(p.x, e[ii][0][3], acc3);
                    acc0 = fmaf(p.y, e[ii][1][0], acc0);
                    acc1 = fmaf(p.y, e[ii][1][1], acc1);
                    acc2 = fmaf(p.y, e[ii][1][2], acc2);
                    acc3 = fmaf(p.y, e[ii][1][3], acc3);
                    acc0 = fmaf(p.z, e[ii][2][0], acc0);
                    acc1 = fmaf(p.z, e[ii][2][1], acc1);
                    acc2 = fmaf(p.z, e[ii][2][2], acc2);
                    acc3 = fmaf(p.z, e[ii][2][3], acc3);
                    acc0 = fmaf(p.w, e[ii][3][0], acc0);
                    acc1 = fmaf(p.w, e[ii][3][1], acc1);
                    acc2 = fmaf(p.w, e[ii][3][2], acc2);
                    acc3 = fmaf(p.w, e[ii][3][3], acc3);
                }
                off += lp0;
                // 16-lane butterfly per accumulator, pure DPP (no DS pipe)
                acc0 = dpp_add<0xB1>(acc0); acc0 = dpp_add<0x4E>(acc0);
                acc0 = dpp_add<0x124>(acc0); acc0 = dpp_add<0x128>(acc0);
                acc1 = dpp_add<0xB1>(acc1); acc1 = dpp_add<0x4E>(acc1);
                acc1 = dpp_add<0x124>(acc1); acc1 = dpp_add<0x128>(acc1);
                acc2 = dpp_add<0xB1>(acc2); acc2 = dpp_add<0x4E>(acc2);
                acc2 = dpp_add<0x124>(acc2); acc2 = dpp_add<0x128>(acc2);
                acc3 = dpp_add<0xB1>(acc3); acc3 = dpp_add<0x4E>(acc3);
                acc3 = dpp_add<0x124>(acc3); acc3 = dpp_add<0x128>(acc3);
                // select this lane's column (c = g&3)
                float sel  = (g & 1) ? acc1 : acc0;
                float selh = (g & 1) ? acc3 : acc2;
                sel = (g & 2) ? selh : sel;
                const float anew = sel * sc;
                if (g < 4) {
                    a = anew;
                    pbuf[cb ^ 1][cj] = anew;
                }
                cb ^= 1;
                BAR();                       // lgkm-only barrier per step
            }
        }
        #pragma unroll
        for (int u = 0; u < 8; ++u) curl[u] = nxtl[u];
    }

    // ---- log_z = off + log(sum_j A[j]); nll = log_z - score ----
    float as = (g < 4) ? a : 0.f;
    #pragma unroll
    for (int o = 32; o > 0; o >>= 1) as += __shfl_down(as, o, 64);
    if ((tid & 63) == 0) ared[tid >> 6] = as;
    __syncthreads();
    if (tid == 0) {
        float tot = 0.f;
        #pragma unroll
        for (int w = 0; w < NT / 64; ++w) tot += ared[w];
        const float logz = off + __logf(tot);
        atomicAdd(out, logz - score);
    }
}

extern "C" void kernel_launch(void* const* d_in, const int* in_sizes, int n_in,
                              void* d_out, int out_size, void* d_ws, size_t ws_size,
                              hipStream_t stream) {
    const float* logits   = (const float*)d_in[0];
    const int*   labels   = (const int*)d_in[1];
    const int*   seq_lens = (const int*)d_in[2];
    const float* trans    = (const float*)d_in[3];
    float* out = (float*)d_out;

    (void)hipMemsetAsync(out, 0, sizeof(float), stream);
    crf_nll_kernel<<<dim3(Bdim), dim3(NT), 0, stream>>>(
        logits, labels, seq_lens, trans, out);
}